// Round 12
// baseline (378.802 us; speedup 1.0000x reference)
//
#include <hip/hip_runtime.h>

// Morphological skeleton, 16 x 1024 x 1024 f32.
// skel = sum_{k=0..20} ( e_k - dilate3x3(e_{k+1}) ),  e_0 = x, e_{k+1} = erode3x3(e_k)
// (reduce_window SAME semantics: windows clamp at image borders).
//
// Register-resident vertical pipeline, zero LDS tile. 3 dispatches x G=7 fused
// erosion stages. One wave (64 lanes x float2) owns a 128-col band and sweeps
// 48 rows in 24 two-row steps.
//
// Round-16 change vs round 15 (303 us): deepen load->use distances past
// memory latency. Evidence: residency is pinned (~15% occupancy at 88 VGPR /
// 4608 waves): per-step time = issue(~440cy) + stall(~700cy from VALUBusy 46%
// at ~1.2 waves/SIMD). The ~700cy stall matches L2-miss/L3-hit latency (the
// 4-array working set is 256MB = L3-sized, L2 mostly misses): input prefetch
// was consumed 1 step (~440cy) after issue, skel seed ~1.5 steps. R5's DPP
// win (-10%) was exactly "remove latency from the per-step stall"; this
// applies it to global loads:
//  (a) input prefetch 4-row deep: two parity pairs pf0/pf1 (STATIC indices
//      via alternating call sites); rows t+4,t+5 issued at step t, consumed
//      at step t+4 (~2000cy in flight);
//  (b) skel seed via acc ring 8->10 slots: rows t+2,t+3 into slots 8,9 at
//      step t, consumed by stage-0 at step t+2 start + 2 shifts (~1400cy);
//  (c) phases rebalanced to even pair counts: WARM 2 | GUARD 6 | STEADY 10 |
//      DRAIN 6 (all start at parity P0).
//
// Phase-range desk-proofs (interior, RCH=32, t0 = y0-8, steps t += 2):
//  - pair parity: step index i (t = t0+2i): P0 for even i; phases start at
//    i = 0,2,8,18 (all even) with even lengths -> all pf slots static.
//  - WARM x2    t = y0-8, y0-6 : erode+rotate only; prefetch rows <= y0-1,
//    in-image (interior y0 >= 32); no acc/shift/seeds/stores.
//  - GUARD x6   t = y0-4..y0+6 : guarded stores/seeds. Stage-0 garbage +=
//    on rows < y0 is never emitted. Seeds rows t+2,t+3 guarded to
//    [y0,y0+RCH): t=y0-2 seeds y0,y0+1 (earliest needed); ... t=y0+6 seeds
//    y0+8,y0+9. E-write only er1 = y0 (t = y0+6). No emits (t < y0+8).
//  - STEADY x10 t = y0+8..y0+26: ALL unconditional. emits rows t-8,t-7 in
//    [y0,y0+19]; e-writes er0 in [y0+1,y0+19], er1 in [y0+2,y0+20]; seeds
//    rows t+2,t+3 in [y0+10,y0+29]; prefetch rows t+4,t+5 <= y0+31 <= 991 <
//    H. All statically in-range.
//  - DRAIN x6   t = y0+28..y0+38: emits y0+20..y0+31; e-writes er0 y0+21..
//    y0+31, er1 y0+22..y0+31 (y0+32 guarded off); seeds y0+30,y0+31 at
//    t=y0+28, rest off; prefetch guard n <= y0+39 (max consumed row y0+39 at
//    t=y0+38 was prefetched at t=y0+34 <= y0+39 OK; y0+39 <= 999 < H).
//  - coverage: emits y0..y0+31; e-rows y0 (GUARD) + y0+1..y0+31 (S+D); seeds
//    y0..y0+9 (GUARD) + y0+10..y0+29 (S) + y0+30,31 (D), each exactly once.
//  - ring algebra (10 slots): entering step t, slot j = row t-8+j (j=0..9).
//    Stage s writes rows t-s-2 -> slot 6-s, t-s-1 -> slot 7-s (slots 0..7
//    as before). Emit reads slots 0,1. Order: emit, shift acc[j]=acc[j+2]
//    (j=0..7), seed slots 8,9 = rows t+2,t+3. Row r: seeded end of step r-2
//    (slot 8), slot 6 entering r+2 (stage-0 += there), slot 0 entering r+8
//    (emitted after stage-6's same-step write).
//  - seed->consume distance: end of step r-2 -> start of step r+2 = 2 full
//    steps (~1400cy); pf distance: issue during t -> consume at t+4 start
//    (~2000cy).
//  - interior iff 32 <= y0 <= H-RCH-32 = 960 (warm cone >= y0-8 >= 24;
//    prefetch max row y0+39 <= 999 < H).
//
// Band geometry (desk-verified disjoint cover):
//  x0 = (b==0) ? 0 : (b==8) ? 896 : 112*b;  gx = x0 + 2*lane
//  owned: b0 [0,120), b1..b7 [112b+8, 112(b+1)+8), b8 [904,1024).
//  leftEdge only b0 lane 0; rightEdge only b8 lane 63. 8-col halo each side
//  absorbs 1 col/stage DPP bound-lane garbage (7 erodes + 1 dilate = 8).
//
// Other invariants from R13-R15 unchanged (two-row stage algebra, OOB +BIG
// rows harmless in min chains / masked in EDGE dilates, disjoint band write
// ownership => the skel read-modify-write never races).

static constexpr int W = 1024, H = 1024, NIMG = 16;
static constexpr int RCH = 32;           // output rows per wave
static constexpr int WPB = 2;            // waves per workgroup
static constexpr int NBAND = 9;          // 128-col bands
static constexpr float BIG = 3.0e38f;

__device__ __forceinline__ float min3f(float a, float b, float c) { return fminf(fminf(a, b), c); }
__device__ __forceinline__ float max3f(float a, float b, float c) { return fmaxf(fmaxf(a, b), c); }

// DPP whole-wave shifts (gfx9/CDNA-only modes; VALU pipe, no DS).
// wave_shr:1 = 0x138 -> lane i reads lane i-1; lane 0 = 0.
// wave_shl:1 = 0x130 -> lane i reads lane i+1; lane 63 = 0.
__device__ __forceinline__ float dpp_left(float v) {
    return __int_as_float(__builtin_amdgcn_mov_dpp(__float_as_int(v), 0x138, 0xF, 0xF, true));
}
__device__ __forceinline__ float dpp_right(float v) {
    return __int_as_float(__builtin_amdgcn_mov_dpp(__float_as_int(v), 0x130, 0xF, 0xF, true));
}

// MODE: 0 = WARM   (pipeline fill: erode+rotate only)
//       1 = GUARD  (all stores/seeds under runtime range checks)
//       2 = STEADY (all loads/stores unconditional; interior chunks only)
// pf: this step's parity pair (rows t,t+1); refills itself with rows t+4,t+5.
template<bool FIRST, bool WRITE_E, bool EDGE, bool LE, bool RE, int MODE>
__device__ __forceinline__
void pipe_step2(int t, int y0, int gx,
                bool leftEdge, bool rightEdge, bool lane_ok,
                const float* __restrict__ in, float* __restrict__ eo,
                float* __restrict__ sk,
                float2 (&OB)[7], float2 (&MB)[7], float2& OD, float2& MD,
                float2 (&acc)[10], float2 (&pf)[2])
{
    // consume input rows t, t+1 (OOB rows +BIG: erode identity)
    float2 cur0, cur1;
    if (!EDGE || (unsigned)t < (unsigned)H)       cur0 = pf[0];
    else                                          cur0 = make_float2(BIG, BIG);
    if (!EDGE || (unsigned)(t + 1) < (unsigned)H) cur1 = pf[1];
    else                                          cur1 = make_float2(BIG, BIG);
    // prefetch rows t+4, t+5 into the pair just consumed (read at step t+4)
    {
        const int n0 = t + 4, n1 = t + 5;
        if (MODE != 1 || ((!EDGE || (unsigned)n0 < (unsigned)H) && n0 <= y0 + RCH + 7))
            pf[0] = *(const float2*)&in[(size_t)n0 * W + gx];
        if (MODE != 1 || ((!EDGE || (unsigned)n1 < (unsigned)H) && n1 <= y0 + RCH + 7))
            pf[1] = *(const float2*)&in[(size_t)n1 * W + gx];
    }

#pragma unroll
    for (int s = 0; s < 7; ++s) {
        const float2 fOld = OB[s];   // f_s(t-s-2)
        const float2 fMid = MB[s];   // f_s(t-s-1)

        // ---- erode both rows: en0 = f_{s+1}(t-s-1), en1 = f_{s+1}(t-s) ----
        float2 vm0, vm1;
        vm0.x = min3f(fOld.x, fMid.x, cur0.x);
        vm0.y = min3f(fOld.y, fMid.y, cur0.y);
        vm1.x = min3f(fMid.x, cur0.x, cur1.x);
        vm1.y = min3f(fMid.y, cur0.y, cur1.y);
        float l0 = dpp_left(vm0.y), r0 = dpp_right(vm0.x);
        float l1 = dpp_left(vm1.y), r1 = dpp_right(vm1.x);
        if (LE && leftEdge)  { l0 = BIG; l1 = BIG; }
        if (RE && rightEdge) { r0 = BIG; r1 = BIG; }
        float2 en0, en1;
        en0.x = min3f(l0,    vm0.x, vm0.y);
        en0.y = min3f(vm0.x, vm0.y, r0);
        en1.x = min3f(l1,    vm1.x, vm1.y);
        en1.y = min3f(vm1.x, vm1.y, r1);

        if (MODE != 0) {
            // ---- dilate of f_{s+1}: centers t-s-2 (dn0), t-s-1 (dn1) ----
            float2 gOld, gMid;   // f_{s+1}(t-s-3), f_{s+1}(t-s-2): pre-update
            if (s < 6) { gOld = OB[s + 1]; gMid = MB[s + 1]; }
            else       { gOld = OD;        gMid = MD;        }
            float2 vx0, vx1;
            if (!EDGE) {
                vx0.x = max3f(gOld.x, gMid.x, en0.x);
                vx0.y = max3f(gOld.y, gMid.y, en0.y);
                vx1.x = max3f(gMid.x, en0.x, en1.x);
                vx1.y = max3f(gMid.y, en0.y, en1.y);
            } else {
                const bool topOK0 = (t - s - 3) >= 0, botOK0 = (t - s - 1) < H;
                const bool topOK1 = (t - s - 2) >= 0, botOK1 = (t - s) < H;
                vx0.x = max3f(topOK0 ? gOld.x : -BIG, gMid.x, botOK0 ? en0.x : -BIG);
                vx0.y = max3f(topOK0 ? gOld.y : -BIG, gMid.y, botOK0 ? en0.y : -BIG);
                vx1.x = max3f(topOK1 ? gMid.x : -BIG, en0.x, botOK1 ? en1.x : -BIG);
                vx1.y = max3f(topOK1 ? gMid.y : -BIG, en0.y, botOK1 ? en1.y : -BIG);
            }
            float dl0 = dpp_left(vx0.y), dr0 = dpp_right(vx0.x);
            float dl1 = dpp_left(vx1.y), dr1 = dpp_right(vx1.x);
            if (LE && leftEdge)  { dl0 = -BIG; dl1 = -BIG; }
            if (RE && rightEdge) { dr0 = -BIG; dr1 = -BIG; }
            float2 dn0, dn1;
            dn0.x = max3f(dl0,   vx0.x, vx0.y);
            dn0.y = max3f(vx0.x, vx0.y, dr0);
            dn1.x = max3f(dl1,   vx1.x, vx1.y);
            dn1.y = max3f(vx1.x, vx1.y, dr1);

            // terms: row t-s-2 -> slot 6-s; row t-s-1 -> slot 7-s
            if (FIRST && s == 0) {
                acc[6].x = fOld.x - dn0.x;  acc[6].y = fOld.y - dn0.y;
                acc[7].x = fMid.x - dn1.x;  acc[7].y = fMid.y - dn1.y;
            } else {
                acc[6 - s].x += fOld.x - dn0.x;  acc[6 - s].y += fOld.y - dn0.y;
                acc[7 - s].x += fMid.x - dn1.x;  acc[7 - s].y += fMid.y - dn1.y;
            }
        }

        // rotate: buffers take the two incoming rows
        OB[s] = cur0;
        MB[s] = cur1;

        if (s == 6) {
            if (WRITE_E && MODE != 0) {
                const int er0 = t - 7, er1 = t - 6;   // f_7 rows
                if (MODE == 2) {
                    if (lane_ok) {
                        *(float2*)&eo[(size_t)er0 * W + gx] = en0;
                        *(float2*)&eo[(size_t)er1 * W + gx] = en1;
                    }
                } else {
                    if (er0 >= y0 && er0 < y0 + RCH && lane_ok)
                        *(float2*)&eo[(size_t)er0 * W + gx] = en0;
                    if (er1 >= y0 && er1 < y0 + RCH && lane_ok)
                        *(float2*)&eo[(size_t)er1 * W + gx] = en1;
                }
            }
            OD = en0;
            MD = en1;
        }
        cur0 = en0;
        cur1 = en1;
    }

    if (MODE != 0) {
        // ---- emit completed rows t-8, t-7 (slots 0,1) ----
        if (MODE == 2) {
            if (lane_ok) {
                *(float2*)&sk[(size_t)(t - 8) * W + gx] = acc[0];
                *(float2*)&sk[(size_t)(t - 7) * W + gx] = acc[1];
            }
        } else {
            if (t >= y0 + 8 && lane_ok) {
                *(float2*)&sk[(size_t)(t - 8) * W + gx] = acc[0];
                *(float2*)&sk[(size_t)(t - 7) * W + gx] = acc[1];
            }
        }
        // one shift per 2-row step (10-slot ring)
#pragma unroll
        for (int j = 0; j < 8; ++j) acc[j] = acc[j + 2];
        // seed slots 8,9 (rows t+2, t+3) with OLD skel; stage-0 += at t+4's
        // predecessor chain (2 full steps of latency cover)
        if (!FIRST) {
            if (MODE == 2) {
                acc[8] = *(const float2*)&sk[(size_t)(t + 2) * W + gx];
                acc[9] = *(const float2*)&sk[(size_t)(t + 3) * W + gx];
            } else {
                if (t + 2 >= y0 && t + 2 < y0 + RCH)
                    acc[8] = *(const float2*)&sk[(size_t)(t + 2) * W + gx];
                if (t + 3 >= y0 && t + 3 < y0 + RCH)
                    acc[9] = *(const float2*)&sk[(size_t)(t + 3) * W + gx];
            }
        }
    }
}

template<bool FIRST, bool WRITE_E, bool LE, bool RE>
__device__ __forceinline__
void sweep_int(int y0, int gx, bool leftEdge, bool rightEdge, bool lane_ok,
               const float* __restrict__ in, float* __restrict__ eo,
               float* __restrict__ sk)
{
    float2 OB[7], MB[7], OD, MD, acc[10], pf0[2], pf1[2];
    const float2 big2 = make_float2(BIG, BIG);
    const float2 z2   = make_float2(0.f, 0.f);
#pragma unroll
    for (int s = 0; s < 7; ++s) { OB[s] = big2; MB[s] = big2; }
    OD = big2; MD = big2;
#pragma unroll
    for (int j = 0; j < 10; ++j) acc[j] = z2;
    // interior: rows y0-8..y0-5 always in-image
    pf0[0] = *(const float2*)&in[(size_t)(y0 - 8) * W + gx];
    pf0[1] = *(const float2*)&in[(size_t)(y0 - 7) * W + gx];
    pf1[0] = *(const float2*)&in[(size_t)(y0 - 6) * W + gx];
    pf1[1] = *(const float2*)&in[(size_t)(y0 - 5) * W + gx];

    int t = y0 - 8;
    // WARM pair: t = y0-8 (P0), y0-6 (P1)
    pipe_step2<FIRST, WRITE_E, false, LE, RE, 0>(t,     y0, gx, leftEdge, rightEdge, lane_ok,
                                                 in, eo, sk, OB, MB, OD, MD, acc, pf0);
    pipe_step2<FIRST, WRITE_E, false, LE, RE, 0>(t + 2, y0, gx, leftEdge, rightEdge, lane_ok,
                                                 in, eo, sk, OB, MB, OD, MD, acc, pf1);
    t += 4;
#pragma unroll 1
    for (int i = 0; i < 3; ++i, t += 4) {   // GUARD: t = y0-4 .. y0+6
        pipe_step2<FIRST, WRITE_E, false, LE, RE, 1>(t,     y0, gx, leftEdge, rightEdge, lane_ok,
                                                     in, eo, sk, OB, MB, OD, MD, acc, pf0);
        pipe_step2<FIRST, WRITE_E, false, LE, RE, 1>(t + 2, y0, gx, leftEdge, rightEdge, lane_ok,
                                                     in, eo, sk, OB, MB, OD, MD, acc, pf1);
    }
#pragma unroll 1
    for (int i = 0; i < 5; ++i, t += 4) {   // STEADY: t = y0+8 .. y0+26
        pipe_step2<FIRST, WRITE_E, false, LE, RE, 2>(t,     y0, gx, leftEdge, rightEdge, lane_ok,
                                                     in, eo, sk, OB, MB, OD, MD, acc, pf0);
        pipe_step2<FIRST, WRITE_E, false, LE, RE, 2>(t + 2, y0, gx, leftEdge, rightEdge, lane_ok,
                                                     in, eo, sk, OB, MB, OD, MD, acc, pf1);
    }
#pragma unroll 1
    for (int i = 0; i < 3; ++i, t += 4) {   // DRAIN: t = y0+28 .. y0+38
        pipe_step2<FIRST, WRITE_E, false, LE, RE, 1>(t,     y0, gx, leftEdge, rightEdge, lane_ok,
                                                     in, eo, sk, OB, MB, OD, MD, acc, pf0);
        pipe_step2<FIRST, WRITE_E, false, LE, RE, 1>(t + 2, y0, gx, leftEdge, rightEdge, lane_ok,
                                                     in, eo, sk, OB, MB, OD, MD, acc, pf1);
    }
}

template<bool FIRST, bool WRITE_E, bool LE, bool RE>
__device__ __forceinline__
void sweep_edge(int y0, int gx, bool leftEdge, bool rightEdge, bool lane_ok,
                const float* __restrict__ in, float* __restrict__ eo,
                float* __restrict__ sk)
{
    float2 OB[7], MB[7], OD, MD, acc[10], pf0[2], pf1[2];
    const float2 big2 = make_float2(BIG, BIG);
    const float2 z2   = make_float2(0.f, 0.f);
#pragma unroll
    for (int s = 0; s < 7; ++s) { OB[s] = big2; MB[s] = big2; }
    OD = big2; MD = big2;
#pragma unroll
    for (int j = 0; j < 10; ++j) acc[j] = z2;
    pf0[0] = big2; pf0[1] = big2; pf1[0] = big2; pf1[1] = big2;
    {
        const int r0 = y0 - 8, r1 = y0 - 7, r2 = y0 - 6, r3 = y0 - 5;
        if (r0 >= 0) pf0[0] = *(const float2*)&in[(size_t)r0 * W + gx];
        if (r1 >= 0) pf0[1] = *(const float2*)&in[(size_t)r1 * W + gx];
        if (r2 >= 0) pf1[0] = *(const float2*)&in[(size_t)r2 * W + gx];
        if (r3 >= 0) pf1[1] = *(const float2*)&in[(size_t)r3 * W + gx];
    }

    int t = y0 - 8;
#pragma unroll 1
    for (int i = 0; i < 12; ++i, t += 4) {  // all-GUARD, 24 steps
        pipe_step2<FIRST, WRITE_E, true, LE, RE, 1>(t,     y0, gx, leftEdge, rightEdge, lane_ok,
                                                    in, eo, sk, OB, MB, OD, MD, acc, pf0);
        pipe_step2<FIRST, WRITE_E, true, LE, RE, 1>(t + 2, y0, gx, leftEdge, rightEdge, lane_ok,
                                                    in, eo, sk, OB, MB, OD, MD, acc, pf1);
    }
}

template<bool FIRST, bool WRITE_E>
__global__ __launch_bounds__(WPB * 64)
void skel_pipe(const float* __restrict__ ein, float* __restrict__ eout,
               float* __restrict__ skel)
{
    const int lane = threadIdx.x;          // 64 lanes; threadIdx.y selects the wave
    const int bx = blockIdx.x;             // band 0..8
    const int y0 = (blockIdx.y * WPB + (int)threadIdx.y) * RCH;  // private row chunk
    const int img = blockIdx.z;
    const int x0 = (bx == 0) ? 0 : ((bx == NBAND - 1) ? (W - 128) : 112 * bx);
    const int gx = x0 + 2 * lane;          // covers cols gx, gx+1; max 896+126=1022

    const size_t base = (size_t)img * (size_t)(W * H);
    const float* __restrict__ in = ein + base;
    float* __restrict__ eo = eout + base;
    float* __restrict__ sk = skel + base;

    const bool leftEdge  = (gx == 0);
    const bool rightEdge = (gx + 2 == W);
    // disjoint write ownership (bands overlap in compute, never in writes)
    const int own_lo = (bx == 0) ? 0 : 112 * bx + 8;
    const int own_hi = (bx == NBAND - 1) ? W : 112 * (bx + 1) + 8;
    const bool lane_ok = (gx >= own_lo) && (gx < own_hi);

    // interior iff 32 <= y0 <= H-RCH-32 (= 960): full warm-up cone in-image,
    // prefetch max row y0+39 <= 999 < H
    const bool interior = (y0 >= 32 && y0 <= H - RCH - 32);

    if (bx == 0) {
        if (interior) sweep_int <FIRST, WRITE_E, true,  false>(y0, gx, leftEdge, rightEdge, lane_ok, in, eo, sk);
        else          sweep_edge<FIRST, WRITE_E, true,  false>(y0, gx, leftEdge, rightEdge, lane_ok, in, eo, sk);
    } else if (bx == NBAND - 1) {
        if (interior) sweep_int <FIRST, WRITE_E, false, true >(y0, gx, leftEdge, rightEdge, lane_ok, in, eo, sk);
        else          sweep_edge<FIRST, WRITE_E, false, true >(y0, gx, leftEdge, rightEdge, lane_ok, in, eo, sk);
    } else {
        if (interior) sweep_int <FIRST, WRITE_E, false, false>(y0, gx, leftEdge, rightEdge, lane_ok, in, eo, sk);
        else          sweep_edge<FIRST, WRITE_E, false, false>(y0, gx, leftEdge, rightEdge, lane_ok, in, eo, sk);
    }
}

extern "C" void kernel_launch(void* const* d_in, const int* in_sizes, int n_in,
                              void* d_out, int out_size, void* d_ws, size_t ws_size,
                              hipStream_t stream)
{
    const float* x = (const float*)d_in[0];
    float* skel = (float*)d_out;
    const size_t n = (size_t)NIMG * W * H;

    float* e0 = (float*)d_ws;
    float* e1 = e0 + n;

    dim3 grid(NBAND, H / (RCH * WPB), NIMG);   // 9 x 16 x 16 = 2304 WGs = 9/CU
    dim3 block(64, WPB);

    // steps 0-6: x -> e0 ; 7-13: e0 -> e1 ; 14-20: e1 -> (none)
    skel_pipe<true,  true ><<<grid, block, 0, stream>>>(x,  e0, skel);
    skel_pipe<false, true ><<<grid, block, 0, stream>>>(e0, e1, skel);
    skel_pipe<false, false><<<grid, block, 0, stream>>>(e1, e0, skel);
}

// Round 13
// 312.461 us; speedup vs baseline: 1.2123x; 1.2123x over previous
//
#include <hip/hip_runtime.h>

// Morphological skeleton, 16 x 1024 x 1024 f32.
// skel = sum_{k=0..20} ( e_k - dilate3x3(e_{k+1}) ),  e_0 = x, e_{k+1} = erode3x3(e_k)
// (reduce_window SAME semantics: windows clamp at image borders).
//
// Round-17: TWO-dispatch fusion (G=10 + G=11 stages), replacing the 3 x G=7
// structure. Ledger across 13 configs: issue ~42us/dispatch and stall
// ~48-72us/dispatch are invariant; occupancy pinned ~15%; per-dispatch
// traffic already near-ideal. The untouched lever is dispatch count/total
// traffic: 3 dispatches moved 640 MB; 2 dispatches move 384 MB (-40%), and
// total steps (where the per-step stall lives) drop ~33%, at EQUAL
// per-output stage-visits (2 x 10.5 stages x 1.25 col-inflation x 1.37
// row-overhead at RCH=64 == 3 x 7 x 1.14 x 1.5).
//   d1: G=10, FIRST (acc assign, no skel read), WRITE_E -> e10; skel = partial
//       sum of terms 0..9.
//   d2: G=11 on f_0 = e10, !FIRST (seeds old skel), no e-write; terms 10..20.
// All R11-proven elements carried: float2 lanes, 2-row steps, DPP wave
// shifts, WARM/GUARD/STEADY/DRAIN phase split, LE/RE/EDGE templating,
// ring-seeded skel accumulate, single distance-1 pf pair (R12's deep pf
// reverted: the ring shift consumed seeds 1 step after load anyway).
//
// G-generalized algebra (verified against the G=7 R11 code):
//  - ring: slots 0..G+2; entering step t, slot j = row t-(G+1)+j.
//  - stage s writes rows t-s-2 -> slot G-1-s, t-s-1 -> slot G-s.
//  - FIRST && s==0: ASSIGN slots G-1,G (no old-skel).
//  - s==G-1: en0/en1 = f_G rows t-G, t-G+1 -> e-write er0=t-G, er1=t-G+1.
//  - emit rows t-(G+1), t-G from slots 0,1 when t >= y0+G+1.
//  - shift acc[j]=acc[j+2], j=0..G; seeds (!FIRST) slots G+1,G+2 <- skel rows
//    t+2,t+3 (guard [y0,y0+RCH)).
//  - pf guard (MODE 1): row <= y0+RCH+G (= max consumed row t_last+1).
//  - t0 = y0-(G+1) (t odd for G=10, even for G=11 -- all indexing absolute).
//
// Phase counts (RCH=64): TOTAL = RCH/2+G+1; WARM = (G-1-((G+1)&1))/2;
// GUARDN = DRAIN = (G+3+((G+1)&1))/2; STEADY = TOTAL-WARM-2*GUARDN.
//  G=10: 43 = 4+7+25+7, t: WARM y0-11..y0-5 | GUARD y0-3..y0+9 | STEADY
//  y0+11..y0+59 | DRAIN y0+61..y0+73.
//  G=11: 44 = 5+7+25+7, t: y0-12..y0-4 | y0-2..y0+10 | y0+12..y0+60 |
//  y0+62..y0+74.
// Desk-proofs (interior):
//  - STEADY unconditional ranges all statically in [y0, y0+RCH): emits
//    t-(G+1),t-G in [y0,y0+49]; e-writes (G=10) t-10,t-9 in [y0+1,y0+50];
//    seeds (G=11) t+2,t+3 in [y0+14,y0+63]; pf rows <= y0+63 <= 959 < H.
//  - coverage (G=10): e-rows y0 (GUARD t=y0+9, er1) + y0+1..y0+50 (STEADY)
//    + y0+51..y0+63 (DRAIN, y0+64 guarded off); emits y0..y0+49 + y0+50..
//    y0+63. (G=11): seeds y0..y0+13 (GUARD) + y0+14..y0+63 (STEADY), each
//    exactly once; emits y0..y0+63.
//  - seed->consume: row r seeded end of step r-2 (slot G+1) or r-3 (G+2),
//    one shift moves it to slot G-1/G, stage-0 += at step r+2, emitted at
//    step r+G+1 after stage-(G-1)'s same-step write.
//  - interior iff 64 <= y0 <= H-RCH-64 = 896 (t0 >= 52 >= 0; max touched row
//    y0+RCH+G <= 971 < H). y0 = 0, 960 take the all-GUARD EDGE path.
//
// Band geometry (both dispatches; NBAND=10, 128-col float2 bands):
//  x0 = (b==0)?0 : (b==9)?896 : 100b; owned: b0 [0,112), b1..b8
//  [100b+12, 100b+112), b9 [912,1024). Disjoint cover of [0,1024); all
//  boundaries even (lane pairs). Halo margins: left 12 (interior) / 16 (b9),
//  right 16 -- >= G+1 = 12 needed for G=11 (DPP bound-lane garbage
//  propagates 1 col/stage, G erodes + 1 dilate). leftEdge only b0 lane 0;
//  rightEdge only b9 lane 63.
//  Ownership disjoint => skel/e writes never race; d1->d2 ordering via
//  stream serialization.

static constexpr int W = 1024, H = 1024, NIMG = 16;
static constexpr int RCH = 64;           // output rows per wave
static constexpr int WPB = 2;            // waves per workgroup
static constexpr int NBAND = 10;         // 128-col bands
static constexpr float BIG = 3.0e38f;

__device__ __forceinline__ float min3f(float a, float b, float c) { return fminf(fminf(a, b), c); }
__device__ __forceinline__ float max3f(float a, float b, float c) { return fmaxf(fmaxf(a, b), c); }

// DPP whole-wave shifts (gfx9/CDNA-only modes; VALU pipe, no DS).
// wave_shr:1 = 0x138 -> lane i reads lane i-1; lane 0 = 0.
// wave_shl:1 = 0x130 -> lane i reads lane i+1; lane 63 = 0.
__device__ __forceinline__ float dpp_left(float v) {
    return __int_as_float(__builtin_amdgcn_mov_dpp(__float_as_int(v), 0x138, 0xF, 0xF, true));
}
__device__ __forceinline__ float dpp_right(float v) {
    return __int_as_float(__builtin_amdgcn_mov_dpp(__float_as_int(v), 0x130, 0xF, 0xF, true));
}

// MODE: 0 = WARM (erode+rotate+pf only), 1 = GUARD (all guarded), 2 = STEADY
// (all loads/stores unconditional; interior only).
template<int G, bool FIRST, bool WRITE_E, bool EDGE, bool LE, bool RE, int MODE>
__device__ __forceinline__
void pipe_step2(int t, int y0, int gx,
                bool leftEdge, bool rightEdge, bool lane_ok,
                const float* __restrict__ in, float* __restrict__ eo,
                float* __restrict__ sk,
                float2 (&OB)[G], float2 (&MB)[G], float2& OD, float2& MD,
                float2 (&acc)[G + 3], float2 (&pf)[2])
{
    // consume input rows t, t+1 (OOB rows +BIG: erode identity)
    float2 cur0, cur1;
    if (!EDGE || (unsigned)t < (unsigned)H)       cur0 = pf[0];
    else                                          cur0 = make_float2(BIG, BIG);
    if (!EDGE || (unsigned)(t + 1) < (unsigned)H) cur1 = pf[1];
    else                                          cur1 = make_float2(BIG, BIG);
    // prefetch rows t+2, t+3 (consumed next step)
    {
        const int n0 = t + 2, n1 = t + 3;
        if (MODE != 1 || ((!EDGE || (unsigned)n0 < (unsigned)H) && n0 <= y0 + RCH + G))
            pf[0] = *(const float2*)&in[(size_t)n0 * W + gx];
        if (MODE != 1 || ((!EDGE || (unsigned)n1 < (unsigned)H) && n1 <= y0 + RCH + G))
            pf[1] = *(const float2*)&in[(size_t)n1 * W + gx];
    }

#pragma unroll
    for (int s = 0; s < G; ++s) {
        const float2 fOld = OB[s];   // f_s(t-s-2)
        const float2 fMid = MB[s];   // f_s(t-s-1)

        // ---- erode both rows: en0 = f_{s+1}(t-s-1), en1 = f_{s+1}(t-s) ----
        float2 vm0, vm1;
        vm0.x = min3f(fOld.x, fMid.x, cur0.x);
        vm0.y = min3f(fOld.y, fMid.y, cur0.y);
        vm1.x = min3f(fMid.x, cur0.x, cur1.x);
        vm1.y = min3f(fMid.y, cur0.y, cur1.y);
        float l0 = dpp_left(vm0.y), r0 = dpp_right(vm0.x);
        float l1 = dpp_left(vm1.y), r1 = dpp_right(vm1.x);
        if (LE && leftEdge)  { l0 = BIG; l1 = BIG; }
        if (RE && rightEdge) { r0 = BIG; r1 = BIG; }
        float2 en0, en1;
        en0.x = min3f(l0,    vm0.x, vm0.y);
        en0.y = min3f(vm0.x, vm0.y, r0);
        en1.x = min3f(l1,    vm1.x, vm1.y);
        en1.y = min3f(vm1.x, vm1.y, r1);

        if (MODE != 0) {
            // ---- dilate of f_{s+1}: centers t-s-2 (dn0), t-s-1 (dn1) ----
            float2 gOld, gMid;   // f_{s+1}(t-s-3), f_{s+1}(t-s-2): pre-update
            if (s < G - 1) { gOld = OB[s + 1]; gMid = MB[s + 1]; }
            else           { gOld = OD;        gMid = MD;        }
            float2 vx0, vx1;
            if (!EDGE) {
                vx0.x = max3f(gOld.x, gMid.x, en0.x);
                vx0.y = max3f(gOld.y, gMid.y, en0.y);
                vx1.x = max3f(gMid.x, en0.x, en1.x);
                vx1.y = max3f(gMid.y, en0.y, en1.y);
            } else {
                const bool topOK0 = (t - s - 3) >= 0, botOK0 = (t - s - 1) < H;
                const bool topOK1 = (t - s - 2) >= 0, botOK1 = (t - s) < H;
                vx0.x = max3f(topOK0 ? gOld.x : -BIG, gMid.x, botOK0 ? en0.x : -BIG);
                vx0.y = max3f(topOK0 ? gOld.y : -BIG, gMid.y, botOK0 ? en0.y : -BIG);
                vx1.x = max3f(topOK1 ? gMid.x : -BIG, en0.x, botOK1 ? en1.x : -BIG);
                vx1.y = max3f(topOK1 ? gMid.y : -BIG, en0.y, botOK1 ? en1.y : -BIG);
            }
            float dl0 = dpp_left(vx0.y), dr0 = dpp_right(vx0.x);
            float dl1 = dpp_left(vx1.y), dr1 = dpp_right(vx1.x);
            if (LE && leftEdge)  { dl0 = -BIG; dl1 = -BIG; }
            if (RE && rightEdge) { dr0 = -BIG; dr1 = -BIG; }
            float2 dn0, dn1;
            dn0.x = max3f(dl0,   vx0.x, vx0.y);
            dn0.y = max3f(vx0.x, vx0.y, dr0);
            dn1.x = max3f(dl1,   vx1.x, vx1.y);
            dn1.y = max3f(vx1.x, vx1.y, dr1);

            // terms: row t-s-2 -> slot G-1-s; row t-s-1 -> slot G-s
            if (FIRST && s == 0) {
                acc[G - 1].x = fOld.x - dn0.x;  acc[G - 1].y = fOld.y - dn0.y;
                acc[G].x     = fMid.x - dn1.x;  acc[G].y     = fMid.y - dn1.y;
            } else {
                acc[G - 1 - s].x += fOld.x - dn0.x;  acc[G - 1 - s].y += fOld.y - dn0.y;
                acc[G - s].x     += fMid.x - dn1.x;  acc[G - s].y     += fMid.y - dn1.y;
            }
        }

        // rotate: buffers take the two incoming rows
        OB[s] = cur0;
        MB[s] = cur1;

        if (s == G - 1) {
            if (WRITE_E && MODE != 0) {
                const int er0 = t - G, er1 = t - G + 1;   // f_G rows
                if (MODE == 2) {
                    if (lane_ok) {
                        *(float2*)&eo[(size_t)er0 * W + gx] = en0;
                        *(float2*)&eo[(size_t)er1 * W + gx] = en1;
                    }
                } else {
                    if (er0 >= y0 && er0 < y0 + RCH && lane_ok)
                        *(float2*)&eo[(size_t)er0 * W + gx] = en0;
                    if (er1 >= y0 && er1 < y0 + RCH && lane_ok)
                        *(float2*)&eo[(size_t)er1 * W + gx] = en1;
                }
            }
            OD = en0;
            MD = en1;
        }
        cur0 = en0;
        cur1 = en1;
    }

    if (MODE != 0) {
        // ---- emit completed rows t-(G+1), t-G (slots 0,1) ----
        if (MODE == 2) {
            if (lane_ok) {
                *(float2*)&sk[(size_t)(t - (G + 1)) * W + gx] = acc[0];
                *(float2*)&sk[(size_t)(t - G) * W + gx]       = acc[1];
            }
        } else {
            if (t >= y0 + G + 1 && lane_ok) {
                *(float2*)&sk[(size_t)(t - (G + 1)) * W + gx] = acc[0];
                *(float2*)&sk[(size_t)(t - G) * W + gx]       = acc[1];
            }
        }
        // one shift per 2-row step
#pragma unroll
        for (int j = 0; j <= G; ++j) acc[j] = acc[j + 2];
        // seed slots G+1,G+2 (rows t+2,t+3) with OLD skel; stage-0 += at t+2
        if (!FIRST) {
            if (MODE == 2) {
                acc[G + 1] = *(const float2*)&sk[(size_t)(t + 2) * W + gx];
                acc[G + 2] = *(const float2*)&sk[(size_t)(t + 3) * W + gx];
            } else {
                if (t + 2 >= y0 && t + 2 < y0 + RCH)
                    acc[G + 1] = *(const float2*)&sk[(size_t)(t + 2) * W + gx];
                if (t + 3 >= y0 && t + 3 < y0 + RCH)
                    acc[G + 2] = *(const float2*)&sk[(size_t)(t + 3) * W + gx];
            }
        }
    }
}

template<int G, bool FIRST, bool WRITE_E, bool LE, bool RE>
__device__ __forceinline__
void sweep_int(int y0, int gx, bool leftEdge, bool rightEdge, bool lane_ok,
               const float* __restrict__ in, float* __restrict__ eo,
               float* __restrict__ sk)
{
    float2 OB[G], MB[G], OD, MD, acc[G + 3], pf[2];
    const float2 big2 = make_float2(BIG, BIG);
    const float2 z2   = make_float2(0.f, 0.f);
#pragma unroll
    for (int s = 0; s < G; ++s) { OB[s] = big2; MB[s] = big2; }
    OD = big2; MD = big2;
#pragma unroll
    for (int j = 0; j < G + 3; ++j) acc[j] = z2;
    // interior: rows y0-(G+1), y0-G always in-image
    pf[0] = *(const float2*)&in[(size_t)(y0 - (G + 1)) * W + gx];
    pf[1] = *(const float2*)&in[(size_t)(y0 - G) * W + gx];

    constexpr int TOTAL  = RCH / 2 + G + 1;
    constexpr int WARM   = (G - 1 - ((G + 1) & 1)) / 2;
    constexpr int GUARDN = (G + 3 + ((G + 1) & 1)) / 2;   // also DRAIN count
    constexpr int STEADY = TOTAL - WARM - 2 * GUARDN;
    static_assert(STEADY > 0, "phase layout");

    int t = y0 - (G + 1);
#pragma unroll
    for (int i = 0; i < WARM; ++i, t += 2)
        pipe_step2<G, FIRST, WRITE_E, false, LE, RE, 0>(t, y0, gx, leftEdge, rightEdge, lane_ok,
                                                        in, eo, sk, OB, MB, OD, MD, acc, pf);
#pragma unroll 1
    for (int i = 0; i < GUARDN; ++i, t += 2)
        pipe_step2<G, FIRST, WRITE_E, false, LE, RE, 1>(t, y0, gx, leftEdge, rightEdge, lane_ok,
                                                        in, eo, sk, OB, MB, OD, MD, acc, pf);
#pragma unroll 1
    for (int i = 0; i < STEADY; ++i, t += 2)
        pipe_step2<G, FIRST, WRITE_E, false, LE, RE, 2>(t, y0, gx, leftEdge, rightEdge, lane_ok,
                                                        in, eo, sk, OB, MB, OD, MD, acc, pf);
#pragma unroll 1
    for (int i = 0; i < GUARDN; ++i, t += 2)
        pipe_step2<G, FIRST, WRITE_E, false, LE, RE, 1>(t, y0, gx, leftEdge, rightEdge, lane_ok,
                                                        in, eo, sk, OB, MB, OD, MD, acc, pf);
}

template<int G, bool FIRST, bool WRITE_E, bool LE, bool RE>
__device__ __forceinline__
void sweep_edge(int y0, int gx, bool leftEdge, bool rightEdge, bool lane_ok,
                const float* __restrict__ in, float* __restrict__ eo,
                float* __restrict__ sk)
{
    float2 OB[G], MB[G], OD, MD, acc[G + 3], pf[2];
    const float2 big2 = make_float2(BIG, BIG);
    const float2 z2   = make_float2(0.f, 0.f);
#pragma unroll
    for (int s = 0; s < G; ++s) { OB[s] = big2; MB[s] = big2; }
    OD = big2; MD = big2;
#pragma unroll
    for (int j = 0; j < G + 3; ++j) acc[j] = z2;
    pf[0] = big2; pf[1] = big2;
    {
        const int r0 = y0 - (G + 1), r1 = y0 - G;
        if (r0 >= 0) pf[0] = *(const float2*)&in[(size_t)r0 * W + gx];
        if (r1 >= 0) pf[1] = *(const float2*)&in[(size_t)r1 * W + gx];
    }

    constexpr int TOTAL = RCH / 2 + G + 1;
    int t = y0 - (G + 1);
#pragma unroll 1
    for (int i = 0; i < TOTAL; ++i, t += 2)
        pipe_step2<G, FIRST, WRITE_E, true, LE, RE, 1>(t, y0, gx, leftEdge, rightEdge, lane_ok,
                                                       in, eo, sk, OB, MB, OD, MD, acc, pf);
}

template<int G, bool FIRST, bool WRITE_E>
__global__ __launch_bounds__(WPB * 64)
void skel_pipe(const float* __restrict__ ein, float* __restrict__ eout,
               float* __restrict__ skel)
{
    const int lane = threadIdx.x;          // 64 lanes; threadIdx.y selects the wave
    const int bx = blockIdx.x;             // band 0..9
    const int y0 = (blockIdx.y * WPB + (int)threadIdx.y) * RCH;  // private row chunk
    const int img = blockIdx.z;
    const int x0 = (bx == 0) ? 0 : ((bx == NBAND - 1) ? (W - 128) : 100 * bx);
    const int gx = x0 + 2 * lane;          // covers cols gx, gx+1; max 896+126=1022

    const size_t base = (size_t)img * (size_t)(W * H);
    const float* __restrict__ in = ein + base;
    float* __restrict__ eo = eout + base;
    float* __restrict__ sk = skel + base;

    const bool leftEdge  = (gx == 0);
    const bool rightEdge = (gx + 2 == W);
    // disjoint write ownership (bands overlap in compute, never in writes)
    const int own_lo = (bx == 0) ? 0 : 100 * bx + 12;
    const int own_hi = (bx == NBAND - 1) ? W : 100 * bx + 112;
    const bool lane_ok = (gx >= own_lo) && (gx < own_hi);

    // interior iff 64 <= y0 <= H-RCH-64 = 896 (header proof)
    const bool interior = (y0 >= 64 && y0 <= H - RCH - 64);

    if (bx == 0) {
        if (interior) sweep_int <G, FIRST, WRITE_E, true,  false>(y0, gx, leftEdge, rightEdge, lane_ok, in, eo, sk);
        else          sweep_edge<G, FIRST, WRITE_E, true,  false>(y0, gx, leftEdge, rightEdge, lane_ok, in, eo, sk);
    } else if (bx == NBAND - 1) {
        if (interior) sweep_int <G, FIRST, WRITE_E, false, true >(y0, gx, leftEdge, rightEdge, lane_ok, in, eo, sk);
        else          sweep_edge<G, FIRST, WRITE_E, false, true >(y0, gx, leftEdge, rightEdge, lane_ok, in, eo, sk);
    } else {
        if (interior) sweep_int <G, FIRST, WRITE_E, false, false>(y0, gx, leftEdge, rightEdge, lane_ok, in, eo, sk);
        else          sweep_edge<G, FIRST, WRITE_E, false, false>(y0, gx, leftEdge, rightEdge, lane_ok, in, eo, sk);
    }
}

extern "C" void kernel_launch(void* const* d_in, const int* in_sizes, int n_in,
                              void* d_out, int out_size, void* d_ws, size_t ws_size,
                              hipStream_t stream)
{
    const float* x = (const float*)d_in[0];
    float* skel = (float*)d_out;

    float* e10 = (float*)d_ws;

    dim3 grid(NBAND, H / (RCH * WPB), NIMG);   // (10, 8, 16) = 1280 WGs
    dim3 block(64, WPB);

    // d1: stages 0-9  : read x,  write e10, write skel partial (terms 0..9)
    // d2: stages 10-20: read e10, read+write skel (terms 10..20 added)
    skel_pipe<10, true,  true ><<<grid, block, 0, stream>>>(x,   e10, skel);
    skel_pipe<11, false, false><<<grid, block, 0, stream>>>(e10, e10, skel);
}